// Round 1
// baseline (1275.797 us; speedup 1.0000x reference)
//
#include <hip/hip_runtime.h>
#include <hip/hip_bf16.h>
#include <math.h>

// Problem constants (B,T,C,H from reference)
static constexpr int Bn = 2, Tn = 2048, Cn = 1024, Hn = 16, HSn = 64;

// ---------------------------------------------------------------------------
// Tiled fp32 GEMM: out[M,N] = A[M,K] @ W[K,N] + bias[N]
// 64x64 block tile, BK=16, 256 threads, 4x4 acc per thread.
// scatter==1: store QKV head-major: out[which][b*H+h][t][d], which=col/C.
// ---------------------------------------------------------------------------
__global__ __launch_bounds__(256) void gemm64(
    const float* __restrict__ A, const float* __restrict__ W,
    const float* __restrict__ bias, float* __restrict__ out,
    int N, int K, int scatter)
{
  __shared__ float Ast[16][68];  // [k][m] transposed; 68*4=272B row stride (16B-aligned)
  __shared__ float Bs [16][68];  // [k][n]

  const int tid = threadIdx.x;
  const int tx = tid & 15;          // 0..15 -> n
  const int ty = tid >> 4;          // 0..15 -> m
  const int arow = tid >> 2;        // 0..63 (m within tile)
  const int ak4  = (tid & 3) * 4;   // k offset 0,4,8,12
  const int brow = tid >> 4;        // 0..15 (k)
  const int bc4  = (tid & 15) * 4;  // n offset

  const int bx = blockIdx.x, by = blockIdx.y;

  const float* Ap = A + (size_t)(by * 64 + arow) * K + ak4;
  const float* Wp = W + (size_t)brow * N + bx * 64 + bc4;

  float acc[4][4];
  #pragma unroll
  for (int i = 0; i < 4; ++i)
    #pragma unroll
    for (int j = 0; j < 4; ++j) acc[i][j] = 0.f;

  for (int k0 = 0; k0 < K; k0 += 16) {
    float4 av = *(const float4*)(Ap + k0);
    float4 bv = *(const float4*)(Wp + (size_t)k0 * N);
    __syncthreads();
    Ast[ak4 + 0][arow] = av.x;
    Ast[ak4 + 1][arow] = av.y;
    Ast[ak4 + 2][arow] = av.z;
    Ast[ak4 + 3][arow] = av.w;
    *(float4*)&Bs[brow][bc4] = bv;
    __syncthreads();
    #pragma unroll
    for (int kk = 0; kk < 16; ++kk) {
      float4 a4 = *(const float4*)&Ast[kk][ty * 4];
      float4 b4 = *(const float4*)&Bs[kk][tx * 4];
      float a[4] = {a4.x, a4.y, a4.z, a4.w};
      float b[4] = {b4.x, b4.y, b4.z, b4.w};
      #pragma unroll
      for (int i = 0; i < 4; ++i)
        #pragma unroll
        for (int j = 0; j < 4; ++j)
          acc[i][j] = fmaf(a[i], b[j], acc[i][j]);
    }
  }

  // epilogue
  if (!scatter) {
    #pragma unroll
    for (int i = 0; i < 4; ++i) {
      int mrow = by * 64 + ty * 4 + i;
      int col0 = bx * 64 + tx * 4;
      float4 o;
      o.x = acc[i][0] + bias[col0 + 0];
      o.y = acc[i][1] + bias[col0 + 1];
      o.z = acc[i][2] + bias[col0 + 2];
      o.w = acc[i][3] + bias[col0 + 3];
      *(float4*)(out + (size_t)mrow * N + col0) = o;
    }
  } else {
    #pragma unroll
    for (int i = 0; i < 4; ++i) {
      int mrow = by * 64 + ty * 4 + i;
      int b = mrow >> 11;      // / T (2048)
      int t = mrow & 2047;
      #pragma unroll
      for (int j = 0; j < 4; ++j) {
        int col = bx * 64 + tx * 4 + j;
        float val = acc[i][j] + bias[col];
        int which = col >> 10;   // / C (1024)
        int c = col & 1023;
        int h = c >> 6;          // / HS (64)
        int d = c & 63;
        size_t idx = (size_t)which * ((size_t)Bn * Hn * Tn * HSn)
                   + ((size_t)(b * Hn + h) * Tn + t) * HSn + d;
        out[idx] = val;
      }
    }
  }
}

// ---------------------------------------------------------------------------
// Flash-style causal attention.
// grid = (B*H, T/64); block = 256 threads.
// Each block: Q-tile of 64 rows; iterate K/V tiles 0..qt with online softmax.
// Thread layout: row = tid/4 (0..63), l4 = tid%4 owns 16 columns / 16 d's.
// y written token-major [B,T,C] for the proj GEMM.
// ---------------------------------------------------------------------------
__global__ __launch_bounds__(256) void attn64(
    const float* __restrict__ qkv, float* __restrict__ y)
{
  const int bh = blockIdx.x;   // b*H + h
  const int qt = blockIdx.y;   // q tile
  const size_t plane = (size_t)Bn * Hn * Tn * HSn;
  const float* Q = qkv + (size_t)bh * Tn * HSn;
  const float* K = qkv + plane + (size_t)bh * Tn * HSn;
  const float* V = qkv + 2 * plane + (size_t)bh * Tn * HSn;

  __shared__ float Qs[64][68];
  __shared__ float Ks[64][68];
  __shared__ float Vs[64][68];
  __shared__ float Ps[64][68];

  const int tid = threadIdx.x;
  const int row = tid >> 2;     // 0..63
  const int l4  = tid & 3;
  const int c0  = l4 * 16;

  // load Q tile (each thread: one row segment of 16 floats)
  {
    const float* src = Q + (size_t)(qt * 64 + row) * HSn + c0;
    #pragma unroll
    for (int n = 0; n < 4; ++n)
      *(float4*)&Qs[row][c0 + 4 * n] = *(const float4*)(src + 4 * n);
  }

  float m = -1e30f, l = 0.f;
  float yacc[16];
  #pragma unroll
  for (int i = 0; i < 16; ++i) yacc[i] = 0.f;

  for (int kt = 0; kt <= qt; ++kt) {
    __syncthreads();   // previous tile fully consumed (also fences Q load)
    {
      const float* ksrc = K + (size_t)(kt * 64 + row) * HSn + c0;
      const float* vsrc = V + (size_t)(kt * 64 + row) * HSn + c0;
      #pragma unroll
      for (int n = 0; n < 4; ++n) {
        *(float4*)&Ks[row][c0 + 4 * n] = *(const float4*)(ksrc + 4 * n);
        *(float4*)&Vs[row][c0 + 4 * n] = *(const float4*)(vsrc + 4 * n);
      }
    }
    __syncthreads();

    // S = (Q K^T) * scale for this thread's 16 columns
    float s[16];
    #pragma unroll
    for (int j = 0; j < 16; ++j) s[j] = 0.f;
    #pragma unroll 4
    for (int d0 = 0; d0 < 64; d0 += 4) {
      float4 q4 = *(const float4*)&Qs[row][d0];
      #pragma unroll
      for (int j = 0; j < 16; ++j) {
        float4 k4 = *(const float4*)&Ks[c0 + j][d0];
        s[j] = fmaf(q4.x, k4.x, s[j]);
        s[j] = fmaf(q4.y, k4.y, s[j]);
        s[j] = fmaf(q4.z, k4.z, s[j]);
        s[j] = fmaf(q4.w, k4.w, s[j]);
      }
    }
    const bool diag = (kt == qt);
    float smax = -1e30f;
    #pragma unroll
    for (int j = 0; j < 16; ++j) {
      s[j] *= 0.125f;                       // 1/sqrt(64)
      if (diag && (c0 + j) > row) s[j] = -1e30f;
      smax = fmaxf(smax, s[j]);
    }
    smax = fmaxf(smax, __shfl_xor(smax, 1));
    smax = fmaxf(smax, __shfl_xor(smax, 2));
    float m_new = fmaxf(m, smax);
    float alpha = __expf(m - m_new);
    float psum = 0.f;
    #pragma unroll
    for (int j = 0; j < 16; ++j) {
      float p = __expf(s[j] - m_new);
      psum += p;
      Ps[row][c0 + j] = p;
    }
    psum += __shfl_xor(psum, 1);
    psum += __shfl_xor(psum, 2);
    l = l * alpha + psum;
    m = m_new;
    #pragma unroll
    for (int i = 0; i < 16; ++i) yacc[i] *= alpha;
    __syncthreads();

    // y += P @ V  (thread's 16 d's)
    for (int j = 0; j < 64; ++j) {
      float p = Ps[row][j];
      #pragma unroll
      for (int i4 = 0; i4 < 4; ++i4) {
        float4 v4 = *(const float4*)&Vs[j][c0 + 4 * i4];
        yacc[4 * i4 + 0] = fmaf(p, v4.x, yacc[4 * i4 + 0]);
        yacc[4 * i4 + 1] = fmaf(p, v4.y, yacc[4 * i4 + 1]);
        yacc[4 * i4 + 2] = fmaf(p, v4.z, yacc[4 * i4 + 2]);
        yacc[4 * i4 + 3] = fmaf(p, v4.w, yacc[4 * i4 + 3]);
      }
    }
  }

  // epilogue: y[b, t, h*HS + d] = yacc / l
  const int b = bh / Hn, h = bh % Hn;
  const int t = qt * 64 + row;
  const float inv = 1.0f / l;
  float* dst = y + ((size_t)(b * Tn + t) * Cn + h * HSn + c0);
  #pragma unroll
  for (int i4 = 0; i4 < 4; ++i4) {
    float4 o;
    o.x = yacc[4 * i4 + 0] * inv;
    o.y = yacc[4 * i4 + 1] * inv;
    o.z = yacc[4 * i4 + 2] * inv;
    o.w = yacc[4 * i4 + 3] * inv;
    *(float4*)(dst + 4 * i4) = o;
  }
}

// ---------------------------------------------------------------------------
extern "C" void kernel_launch(void* const* d_in, const int* in_sizes, int n_in,
                              void* d_out, int out_size, void* d_ws, size_t ws_size,
                              hipStream_t stream) {
  const float* x      = (const float*)d_in[0];
  const float* W_attn = (const float*)d_in[1];
  const float* b_attn = (const float*)d_in[2];
  const float* W_proj = (const float*)d_in[3];
  const float* b_proj = (const float*)d_in[4];
  float* out = (float*)d_out;

  float* qkv  = (float*)d_ws;                                  // 3*B*H*T*HS f32 = 50.3 MB
  float* ybuf = qkv + (size_t)3 * Bn * Hn * Tn * HSn;          // B*T*C f32 = 16.8 MB

  // 1) QKV = x @ W_attn + b_attn, scattered to [3][B,H,T,HS]
  gemm64<<<dim3(3 * Cn / 64, Bn * Tn / 64), 256, 0, stream>>>(
      x, W_attn, b_attn, qkv, 3 * Cn, Cn, 1);

  // 2) causal attention -> ybuf [B,T,C]
  attn64<<<dim3(Bn * Hn, Tn / 64), 256, 0, stream>>>(qkv, ybuf);

  // 3) out = ybuf @ W_proj + b_proj
  gemm64<<<dim3(Cn / 64, Bn * Tn / 64), 256, 0, stream>>>(
      ybuf, W_proj, b_proj, out, Cn, Cn, 0);
}

// Round 2
// 208.125 us; speedup vs baseline: 6.1300x; 6.1300x over previous
//
#include <hip/hip_runtime.h>
#include <math.h>

static constexpr int Bn = 2, Tn = 2048, Cn = 1024, Hn = 16, HSn = 64;
static constexpr int Mrows = Bn * Tn;                 // 4096
static constexpr size_t PL = (size_t)Bn * Hn * Tn * HSn;  // one qkv plane (4.19M)

typedef __attribute__((ext_vector_type(8))) short short8;
typedef __attribute__((ext_vector_type(4))) float f32x4;

__device__ __forceinline__ unsigned short f2bf(float f) {
  unsigned u = __float_as_uint(f);
  unsigned r = (u + 0x7FFFu + ((u >> 16) & 1u)) >> 16;
  return (unsigned short)r;
}

__device__ __forceinline__ void gload_lds16(const void* g, void* l) {
  __builtin_amdgcn_global_load_lds(
      (const __attribute__((address_space(1))) void*)g,
      (__attribute__((address_space(3))) void*)l, 16, 0, 0);
}

// ---------------------------------------------------------------------------
// prep: f32 -> bf16 cast (x), and transpose+cast for weights
// ---------------------------------------------------------------------------
__global__ __launch_bounds__(256) void cast_bf16(const float* __restrict__ src,
                                                 unsigned short* __restrict__ dst, int n4) {
  int i = blockIdx.x * 256 + threadIdx.x;
  if (i < n4) {
    float4 v = ((const float4*)src)[i];
    ushort4 o;
    o.x = f2bf(v.x); o.y = f2bf(v.y); o.z = f2bf(v.z); o.w = f2bf(v.w);
    ((ushort4*)dst)[i] = o;
  }
}

// src [R][Cc] f32  ->  dst [Cc][R] bf16
__global__ __launch_bounds__(256) void transpose_cast(const float* __restrict__ src,
                                                      unsigned short* __restrict__ dst,
                                                      int R, int Cc) {
  __shared__ float tile[32][33];
  int tx = threadIdx.x, ty = threadIdx.y;
  int c0 = blockIdx.x * 32, r0 = blockIdx.y * 32;
  #pragma unroll
  for (int i = 0; i < 4; ++i)
    tile[ty + 8 * i][tx] = src[(size_t)(r0 + ty + 8 * i) * Cc + c0 + tx];
  __syncthreads();
  #pragma unroll
  for (int i = 0; i < 4; ++i)
    dst[(size_t)(c0 + ty + 8 * i) * R + r0 + tx] = f2bf(tile[tx][ty + 8 * i]);
}

// ---------------------------------------------------------------------------
// bf16 MFMA GEMM: A [M][K] bf16, Bt [N][K] bf16 (pre-transposed weights).
// 128x128 tile, BK=32, 4 waves, each wave 64x64 (4x4 fragments 16x16x32).
// LDS fragment-ordered, staged via global_load_lds w/ per-lane global addr.
// MODE 1: qkv epilogue (bias, scatter Q,K head-major + V transposed, bf16)
// MODE 2: f32 out + bias
// ---------------------------------------------------------------------------
template <int MODE>
__global__ __launch_bounds__(256) void gemm128(
    const unsigned short* __restrict__ A, const unsigned short* __restrict__ Bt,
    const float* __restrict__ bias, void* __restrict__ Out, int N, int K)
{
  __shared__ alignas(16) unsigned char lds[16384];   // A frags 8KB, B frags 8KB
  const int tid = threadIdx.x, wave = tid >> 6, lane = tid & 63;
  const int wr = wave >> 1, wc = wave & 1;
  const int tM = blockIdx.y * 128, tN = blockIdx.x * 128;

  f32x4 acc[4][4] = {};

  for (int k0 = 0; k0 < K; k0 += 32) {
    __syncthreads();
    #pragma unroll
    for (int i = 0; i < 2; ++i) {
      int mg = wave * 2 + i;
      const unsigned short* ga =
          A + (size_t)(tM + mg * 16 + (lane & 15)) * K + k0 + (lane >> 4) * 8;
      gload_lds16(ga, &lds[mg * 1024]);
      const unsigned short* gb =
          Bt + (size_t)(tN + mg * 16 + (lane & 15)) * K + k0 + (lane >> 4) * 8;
      gload_lds16(gb, &lds[8192 + mg * 1024]);
    }
    __syncthreads();
    short8 af[4], bfr[4];
    #pragma unroll
    for (int m = 0; m < 4; ++m)
      af[m] = *(const short8*)&lds[(wr * 4 + m) * 1024 + lane * 16];
    #pragma unroll
    for (int n = 0; n < 4; ++n)
      bfr[n] = *(const short8*)&lds[8192 + (wc * 4 + n) * 1024 + lane * 16];
    #pragma unroll
    for (int m = 0; m < 4; ++m)
      #pragma unroll
      for (int n = 0; n < 4; ++n)
        acc[m][n] = __builtin_amdgcn_mfma_f32_16x16x32_bf16(af[m], bfr[n], acc[m][n], 0, 0, 0);
  }

  const int a = lane & 15, hq = lane >> 4;
  if (MODE == 2) {
    float* O = (float*)Out;
    #pragma unroll
    for (int m = 0; m < 4; ++m) {
      #pragma unroll
      for (int n = 0; n < 4; ++n) {
        int c = tN + wc * 64 + n * 16 + a;
        float bv = bias[c];
        int r0 = tM + wr * 64 + m * 16 + hq * 4;
        #pragma unroll
        for (int r = 0; r < 4; ++r)
          O[(size_t)(r0 + r) * N + c] = acc[m][n][r] + bv;
      }
    }
  } else {
    unsigned short* qkv = (unsigned short*)Out;
    #pragma unroll
    for (int m = 0; m < 4; ++m) {
      #pragma unroll
      for (int n = 0; n < 4; ++n) {
        int c = tN + wc * 64 + n * 16 + a;
        float bv = bias[c];
        int which = c >> 10, cc = c & 1023, hh = cc >> 6, d = cc & 63;
        #pragma unroll
        for (int r = 0; r < 4; ++r) {
          int row = tM + wr * 64 + m * 16 + hq * 4 + r;   // b*T + t
          int b = row >> 11, t = row & 2047;
          int bh = b * Hn + hh;
          float v = acc[m][n][r] + bv;
          size_t idx;
          if (which == 2) idx = 2 * PL + ((size_t)bh * HSn + d) * Tn + t;      // V^T [bh][d][t]
          else            idx = (size_t)which * PL + ((size_t)bh * Tn + t) * HSn + d;
          qkv[idx] = f2bf(v);
        }
      }
    }
  }
}

// ---------------------------------------------------------------------------
// Flash attention, bf16 MFMA 16x16x32. grid (BH=32, T/64=32), 256 threads.
// Wave w owns q-rows [w*16, w*16+16). KVBLK=64.
// LDS tiles [64 rows][8 chunks of 16B], chunk' = chunk ^ (row&7) (T2 swizzle).
// ---------------------------------------------------------------------------
__global__ __launch_bounds__(256) void attn_mfma(
    const unsigned short* __restrict__ Qg, const unsigned short* __restrict__ Kg,
    const unsigned short* __restrict__ Vtg, unsigned short* __restrict__ Y)
{
  __shared__ alignas(16) unsigned char lds[33792];
  // Q:[0,8192) K:[8192,16384) Vt:[16384,24576) P: 24576 + wave*2304 (16 rows x 72 bf16)
  const int bh = blockIdx.x, qt = blockIdx.y;
  const int tid = threadIdx.x, wave = tid >> 6, lane = tid & 63;
  const int a = lane & 15, h = lane >> 4;
  const int q0 = qt * 64;
  const unsigned short* Qp = Qg + (size_t)bh * Tn * HSn;
  const unsigned short* Kp = Kg + (size_t)bh * Tn * HSn;
  const unsigned short* Vp = Vtg + (size_t)bh * HSn * Tn;   // [64][2048]
  const int pbase = 24576 + wave * 2304;

  // stage Q tile (swizzled)
  #pragma unroll
  for (int i = 0; i < 2; ++i) {
    int r8 = wave * 16 + i * 8;
    int row = r8 + (lane >> 3);
    int ch = (lane & 7) ^ (row & 7);
    gload_lds16(Qp + (size_t)(q0 + row) * HSn + ch * 8, &lds[r8 * 128]);
  }
  __syncthreads();
  short8 qf[2];
  #pragma unroll
  for (int ks = 0; ks < 2; ++ks) {
    int row = wave * 16 + a;
    int ch = (ks * 4 + h) ^ (row & 7);
    qf[ks] = *(const short8*)&lds[row * 128 + ch * 16];
  }

  f32x4 o[4] = {};
  float mr[4] = {-1e30f, -1e30f, -1e30f, -1e30f};
  float lr[4] = {0.f, 0.f, 0.f, 0.f};

  for (int kt = 0; kt <= qt; ++kt) {
    const int kv0 = kt * 64;
    __syncthreads();
    #pragma unroll
    for (int i = 0; i < 2; ++i) {
      int r8 = wave * 16 + i * 8;
      int row = r8 + (lane >> 3);
      int ch = (lane & 7) ^ (row & 7);
      gload_lds16(Kp + (size_t)(kv0 + row) * HSn + ch * 8, &lds[8192 + r8 * 128]);
      gload_lds16(Vp + (size_t)row * Tn + kv0 + ch * 8, &lds[16384 + r8 * 128]);
    }
    __syncthreads();

    // S = Q K^T
    f32x4 s[4] = {};
    #pragma unroll
    for (int ks = 0; ks < 2; ++ks)
      #pragma unroll
      for (int n = 0; n < 4; ++n) {
        int kr = n * 16 + a;
        int ch = (ks * 4 + h) ^ (kr & 7);
        short8 kf = *(const short8*)&lds[8192 + kr * 128 + ch * 16];
        s[n] = __builtin_amdgcn_mfma_f32_16x16x32_bf16(qf[ks], kf, s[n], 0, 0, 0);
      }

    // scale + causal mask (C layout: row=4h+r, col=16n+a)
    #pragma unroll
    for (int n = 0; n < 4; ++n)
      #pragma unroll
      for (int r = 0; r < 4; ++r) {
        float sv = s[n][r] * 0.125f;
        if (kt == qt && (n * 16 + a) > (wave * 16 + 4 * h + r)) sv = -1e30f;
        s[n][r] = sv;
      }

    // online softmax
    float tmax[4], al[4], ps[4];
    #pragma unroll
    for (int r = 0; r < 4; ++r) {
      float v = fmaxf(fmaxf(s[0][r], s[1][r]), fmaxf(s[2][r], s[3][r]));
      v = fmaxf(v, __shfl_xor(v, 1));
      v = fmaxf(v, __shfl_xor(v, 2));
      v = fmaxf(v, __shfl_xor(v, 4));
      v = fmaxf(v, __shfl_xor(v, 8));
      tmax[r] = v;
    }
    #pragma unroll
    for (int r = 0; r < 4; ++r) {
      float mn = fmaxf(mr[r], tmax[r]);
      al[r] = __expf(mr[r] - mn);
      mr[r] = mn;
      ps[r] = 0.f;
    }
    #pragma unroll
    for (int n = 0; n < 4; ++n)
      #pragma unroll
      for (int r = 0; r < 4; ++r) {
        float p = __expf(s[n][r] - mr[r]);
        s[n][r] = p;
        ps[r] += p;
      }
    #pragma unroll
    for (int r = 0; r < 4; ++r) {
      float v = ps[r];
      v += __shfl_xor(v, 1);
      v += __shfl_xor(v, 2);
      v += __shfl_xor(v, 4);
      v += __shfl_xor(v, 8);
      lr[r] = lr[r] * al[r] + v;
    }
    #pragma unroll
    for (int n = 0; n < 4; ++n)
      #pragma unroll
      for (int r = 0; r < 4; ++r) o[n][r] *= al[r];

    // P -> LDS bf16 (pair-packed b32 writes, conflict-free stride 36 words)
    #pragma unroll
    for (int n = 0; n < 4; ++n)
      #pragma unroll
      for (int r = 0; r < 4; ++r) {
        float other = __shfl_xor(s[n][r], 1);
        if (!(lane & 1)) {
          unsigned w32 = (unsigned)f2bf(s[n][r]) | ((unsigned)f2bf(other) << 16);
          *(unsigned*)&lds[pbase + ((4 * h + r) * 36 + n * 8 + (a >> 1)) * 4] = w32;
        }
      }

    // O += P V
    #pragma unroll
    for (int ks = 0; ks < 2; ++ks) {
      short8 pa = *(const short8*)&lds[pbase + (a * 36 + ks * 16 + h * 4) * 4];
      #pragma unroll
      for (int n = 0; n < 4; ++n) {
        int d = n * 16 + a;
        int ch = (ks * 4 + h) ^ (d & 7);
        short8 vf = *(const short8*)&lds[16384 + d * 128 + ch * 16];
        o[n] = __builtin_amdgcn_mfma_f32_16x16x32_bf16(pa, vf, o[n], 0, 0, 0);
      }
    }
  }

  // epilogue: y[b][t][head*64 + d] bf16
  const int b = bh >> 4, hd = bh & 15;
  #pragma unroll
  for (int n = 0; n < 4; ++n)
    #pragma unroll
    for (int r = 0; r < 4; ++r) {
      int t = q0 + wave * 16 + 4 * h + r;
      int col = hd * 64 + n * 16 + a;
      Y[((size_t)(b * Tn + t)) * Cn + col] = f2bf(o[n][r] / lr[r]);
    }
}

// ---------------------------------------------------------------------------
extern "C" void kernel_launch(void* const* d_in, const int* in_sizes, int n_in,
                              void* d_out, int out_size, void* d_ws, size_t ws_size,
                              hipStream_t stream) {
  const float* x      = (const float*)d_in[0];
  const float* W_attn = (const float*)d_in[1];
  const float* b_attn = (const float*)d_in[2];
  const float* W_proj = (const float*)d_in[3];
  const float* b_proj = (const float*)d_in[4];
  float* out = (float*)d_out;

  unsigned short* xb  = (unsigned short*)d_ws;          // [4096][1024]
  unsigned short* Wab = xb + (size_t)Mrows * Cn;        // [3072][1024]
  unsigned short* Wpb = Wab + (size_t)3 * Cn * Cn;      // [1024][1024]
  unsigned short* qkv = Wpb + (size_t)Cn * Cn;          // 3 planes of PL
  unsigned short* y   = qkv + 3 * PL;                   // [4096][1024]

  cast_bf16<<<(Mrows * Cn / 4 + 255) / 256, 256, 0, stream>>>(x, xb, Mrows * Cn / 4);
  transpose_cast<<<dim3(3 * Cn / 32, Cn / 32), dim3(32, 8), 0, stream>>>(W_attn, Wab, Cn, 3 * Cn);
  transpose_cast<<<dim3(Cn / 32, Cn / 32), dim3(32, 8), 0, stream>>>(W_proj, Wpb, Cn, Cn);

  gemm128<1><<<dim3(3 * Cn / 128, Mrows / 128), 256, 0, stream>>>(xb, Wab, b_attn, qkv, 3 * Cn, Cn);

  attn_mfma<<<dim3(Bn * Hn, Tn / 64), 256, 0, stream>>>(qkv, qkv + PL, qkv + 2 * PL, y);

  gemm128<2><<<dim3(Cn / 128, Mrows / 128), 256, 0, stream>>>(y, Wpb, b_proj, out, Cn, Cn);
}

// Round 4
// 154.227 us; speedup vs baseline: 8.2722x; 1.3495x over previous
//
#include <hip/hip_runtime.h>

static constexpr int Bn = 2, Tn = 2048, Cn = 1024, Hn = 16, HSn = 64;
static constexpr int Mrows = Bn * Tn;                 // 4096
static constexpr size_t PL = (size_t)Bn * Hn * Tn * HSn;  // one qkv plane (4.19M)

typedef __attribute__((ext_vector_type(8))) short short8;
typedef __attribute__((ext_vector_type(4))) float f32x4;

__device__ __forceinline__ unsigned short f2bf(float f) {
  unsigned u = __float_as_uint(f);
  unsigned r = (u + 0x7FFFu + ((u >> 16) & 1u)) >> 16;
  return (unsigned short)r;
}

__device__ __forceinline__ float fexp2(float x) {
  return __builtin_amdgcn_exp2f(x);
}

__device__ __forceinline__ void gload_lds16(const void* g, void* l) {
  __builtin_amdgcn_global_load_lds(
      (const __attribute__((address_space(1))) void*)g,
      (__attribute__((address_space(3))) void*)l, 16, 0, 0);
}

// ---------------------------------------------------------------------------
// prep kernels
// ---------------------------------------------------------------------------
__global__ __launch_bounds__(256) void cast_bf16(const float* __restrict__ src,
                                                 unsigned short* __restrict__ dst, int n4) {
  int i = blockIdx.x * 256 + threadIdx.x;
  if (i < n4) {
    float4 v = ((const float4*)src)[i];
    ushort4 o;
    o.x = f2bf(v.x); o.y = f2bf(v.y); o.z = f2bf(v.z); o.w = f2bf(v.w);
    ((ushort4*)dst)[i] = o;
  }
}

// src [R][Cc] f32  ->  dst [Cc][R] bf16
__global__ __launch_bounds__(256) void transpose_cast(const float* __restrict__ src,
                                                      unsigned short* __restrict__ dst,
                                                      int R, int Cc) {
  __shared__ float tile[32][33];
  int tx = threadIdx.x, ty = threadIdx.y;
  int c0 = blockIdx.x * 32, r0 = blockIdx.y * 32;
  #pragma unroll
  for (int i = 0; i < 4; ++i)
    tile[ty + 8 * i][tx] = src[(size_t)(r0 + ty + 8 * i) * Cc + c0 + tx];
  __syncthreads();
  #pragma unroll
  for (int i = 0; i < 4; ++i)
    dst[(size_t)(c0 + ty + 8 * i) * R + r0 + tx] = f2bf(tile[tx][ty + 8 * i]);
}

// ---------------------------------------------------------------------------
// bf16 MFMA GEMM, 128x128 tile, BK=32, 4 waves.
// MODE 1: qkv epilogue (bias, scatter Q,K head-major + V transposed, bf16)
// MODE 2: f32 out + bias
// ---------------------------------------------------------------------------
template <int MODE>
__global__ __launch_bounds__(256) void gemm128(
    const unsigned short* __restrict__ A, const unsigned short* __restrict__ Bt,
    const float* __restrict__ bias, void* __restrict__ Out, int N, int K)
{
  __shared__ alignas(16) unsigned char lds[16384];
  const int tid = threadIdx.x, wave = tid >> 6, lane = tid & 63;
  const int wr = wave >> 1, wc = wave & 1;
  const int tM = blockIdx.y * 128, tN = blockIdx.x * 128;

  f32x4 acc[4][4] = {};

  for (int k0 = 0; k0 < K; k0 += 32) {
    __syncthreads();
    #pragma unroll
    for (int i = 0; i < 2; ++i) {
      int mg = wave * 2 + i;
      const unsigned short* ga =
          A + (size_t)(tM + mg * 16 + (lane & 15)) * K + k0 + (lane >> 4) * 8;
      gload_lds16(ga, &lds[mg * 1024]);
      const unsigned short* gb =
          Bt + (size_t)(tN + mg * 16 + (lane & 15)) * K + k0 + (lane >> 4) * 8;
      gload_lds16(gb, &lds[8192 + mg * 1024]);
    }
    __syncthreads();
    short8 af[4], bfr[4];
    #pragma unroll
    for (int m = 0; m < 4; ++m)
      af[m] = *(const short8*)&lds[(wr * 4 + m) * 1024 + lane * 16];
    #pragma unroll
    for (int n = 0; n < 4; ++n)
      bfr[n] = *(const short8*)&lds[8192 + (wc * 4 + n) * 1024 + lane * 16];
    #pragma unroll
    for (int m = 0; m < 4; ++m)
      #pragma unroll
      for (int n = 0; n < 4; ++n)
        acc[m][n] = __builtin_amdgcn_mfma_f32_16x16x32_bf16(af[m], bfr[n], acc[m][n], 0, 0, 0);
  }

  const int a = lane & 15, hq = lane >> 4;
  if (MODE == 2) {
    float* O = (float*)Out;
    #pragma unroll
    for (int m = 0; m < 4; ++m) {
      #pragma unroll
      for (int n = 0; n < 4; ++n) {
        int c = tN + wc * 64 + n * 16 + a;
        float bv = bias[c];
        int r0 = tM + wr * 64 + m * 16 + hq * 4;
        #pragma unroll
        for (int r = 0; r < 4; ++r)
          O[(size_t)(r0 + r) * N + c] = acc[m][n][r] + bv;
      }
    }
  } else {
    unsigned short* qkv = (unsigned short*)Out;
    #pragma unroll
    for (int m = 0; m < 4; ++m) {
      #pragma unroll
      for (int n = 0; n < 4; ++n) {
        int c = tN + wc * 64 + n * 16 + a;
        float bv = bias[c];
        int which = c >> 10, cc = c & 1023, hh = cc >> 6, d = cc & 63;
        int row0 = tM + wr * 64 + m * 16 + hq * 4;
        int b = row0 >> 11, t0 = row0 & 2047;
        int bh = b * Hn + hh;
        if (which == 2) {
          // V^T [bh][d][t], 4 consecutive t -> one 8B store
          ushort4 pk;
          pk.x = f2bf(acc[m][n][0] + bv);
          pk.y = f2bf(acc[m][n][1] + bv);
          pk.z = f2bf(acc[m][n][2] + bv);
          pk.w = f2bf(acc[m][n][3] + bv);
          *(ushort4*)&qkv[2 * PL + ((size_t)bh * HSn + d) * Tn + t0] = pk;
        } else {
          #pragma unroll
          for (int r = 0; r < 4; ++r) {
            float v = acc[m][n][r] + bv;
            qkv[(size_t)which * PL + ((size_t)bh * Tn + t0 + r) * HSn + d] = f2bf(v);
          }
        }
      }
    }
  }
}

// ---------------------------------------------------------------------------
// Flash attention, bf16 MFMA 16x16x32, swapped QK^T (reduction lane-local).
// grid (BH=32, 32 remapped->qt), 256 threads; wave w owns q-rows [16w,16w+16).
// LDS rows [64][8 chunks of 16B], chunk' = chunk ^ (row&7).
// ---------------------------------------------------------------------------
__global__ __launch_bounds__(256) void attn_mfma(
    const unsigned short* __restrict__ Qg, const unsigned short* __restrict__ Kg,
    const unsigned short* __restrict__ Vtg, unsigned short* __restrict__ Y)
{
  __shared__ alignas(16) unsigned char lds[34048];
  // Q:[0,8K) K:[8K,16K) Vt:[16K,24K) per-wave: 24576 + wave*2368 (P 2304B + 64B alpha/l)
  const int bh = blockIdx.x;
  const int yb = blockIdx.y;
  const int kq = yb >> 3, jq = yb & 7;
  const int qt = kq * 8 + ((kq & 1) ? (7 - jq) : jq);   // balanced causal remap
  const int tid = threadIdx.x, wave = tid >> 6, lane = tid & 63;
  const int a = lane & 15, h = lane >> 4;
  const int q0 = qt * 64;
  const unsigned short* Qp = Qg + (size_t)bh * Tn * HSn;
  const unsigned short* Kp = Kg + (size_t)bh * Tn * HSn;
  const unsigned short* Vp = Vtg + (size_t)bh * HSn * Tn;   // [64][2048]
  const int pbase = 24576 + wave * 2368;
  const float SC = 0.125f * 1.44269504088896340736f;   // (1/sqrt(64)) * log2(e)

  // stage Q tile (swizzled)
  #pragma unroll
  for (int i = 0; i < 2; ++i) {
    int r8 = wave * 16 + i * 8;
    int row = r8 + (lane >> 3);
    int ch = (lane & 7) ^ (row & 7);
    gload_lds16(Qp + (size_t)(q0 + row) * HSn + ch * 8, &lds[r8 * 128]);
  }
  __syncthreads();
  short8 qf[2];
  #pragma unroll
  for (int ks = 0; ks < 2; ++ks) {
    int row = wave * 16 + a;
    int ch = (ks * 4 + h) ^ (row & 7);
    qf[ks] = *(const short8*)&lds[row * 128 + ch * 16];
  }

  f32x4 o[4] = {};
  float m = -1e30f, l = 0.f;

  for (int kt = 0; kt <= qt; ++kt) {
    const int kv0 = kt * 64;
    __syncthreads();
    #pragma unroll
    for (int i = 0; i < 2; ++i) {
      int r8 = wave * 16 + i * 8;
      int row = r8 + (lane >> 3);
      int ch = (lane & 7) ^ (row & 7);
      gload_lds16(Kp + (size_t)(kv0 + row) * HSn + ch * 8, &lds[8192 + r8 * 128]);
      gload_lds16(Vp + (size_t)row * Tn + kv0 + ch * 8, &lds[16384 + r8 * 128]);
    }
    __syncthreads();

    // S^T = K Q^T : lane (a,h) holds S[kv=n*16+4h+r][q = wave*16+a]
    f32x4 s[4] = {};
    __builtin_amdgcn_s_setprio(1);
    #pragma unroll
    for (int ks = 0; ks < 2; ++ks)
      #pragma unroll
      for (int n = 0; n < 4; ++n) {
        int kr = n * 16 + a;
        int ch = (ks * 4 + h) ^ (kr & 7);
        short8 kf = *(const short8*)&lds[8192 + kr * 128 + ch * 16];
        s[n] = __builtin_amdgcn_mfma_f32_16x16x32_bf16(kf, qf[ks], s[n], 0, 0, 0);
      }
    __builtin_amdgcn_s_setprio(0);

    // scale (log2 domain) + causal mask; per-lane row max
    const bool diag = (kt == qt);
    float pmax = -1e30f;
    #pragma unroll
    for (int n = 0; n < 4; ++n)
      #pragma unroll
      for (int r = 0; r < 4; ++r) {
        float sv = s[n][r] * SC;
        if (diag && (n * 16 + h * 4 + r) > (wave * 16 + a)) sv = -1e30f;
        s[n][r] = sv;
        pmax = fmaxf(pmax, sv);
      }
    pmax = fmaxf(pmax, __shfl_xor(pmax, 16));
    pmax = fmaxf(pmax, __shfl_xor(pmax, 32));
    float mn = fmaxf(m, pmax);
    float alpha = fexp2(m - mn);
    m = mn;
    float psum = 0.f;
    #pragma unroll
    for (int n = 0; n < 4; ++n)
      #pragma unroll
      for (int r = 0; r < 4; ++r) {
        float p = fexp2(s[n][r] - mn);
        s[n][r] = p;
        psum += p;
      }
    psum += __shfl_xor(psum, 16);
    psum += __shfl_xor(psum, 32);
    l = l * alpha + psum;

    if (h == 0) *(float*)&lds[pbase + 2304 + a * 4] = alpha;

    // P -> LDS bf16, lane-local pack: row q=a, words a*36 + n*8 + h*2 (+w)
    #pragma unroll
    for (int n = 0; n < 4; ++n) {
      uint2 w2;
      w2.x = (unsigned)f2bf(s[n][0]) | ((unsigned)f2bf(s[n][1]) << 16);
      w2.y = (unsigned)f2bf(s[n][2]) | ((unsigned)f2bf(s[n][3]) << 16);
      *(uint2*)&lds[pbase + (a * 36 + n * 8 + h * 2) * 4] = w2;
    }

    // O rescale by alpha[q-row 4h+r] (broadcast read)
    f32x4 al4 = *(const f32x4*)&lds[pbase + 2304 + h * 16];
    #pragma unroll
    for (int n = 0; n < 4; ++n)
      #pragma unroll
      for (int r = 0; r < 4; ++r) o[n][r] *= al4[r];

    // O += P V
    __builtin_amdgcn_s_setprio(1);
    #pragma unroll
    for (int ks = 0; ks < 2; ++ks) {
      short8 pa = *(const short8*)&lds[pbase + (a * 36 + ks * 16 + h * 4) * 4];
      #pragma unroll
      for (int n = 0; n < 4; ++n) {
        int d = n * 16 + a;
        int ch = (ks * 4 + h) ^ (d & 7);
        short8 vf = *(const short8*)&lds[16384 + d * 128 + ch * 16];
        o[n] = __builtin_amdgcn_mfma_f32_16x16x32_bf16(pa, vf, o[n], 0, 0, 0);
      }
    }
    __builtin_amdgcn_s_setprio(0);
  }

  // epilogue: divide by l[q-row], y[b][t][head*64+d] bf16
  if (h == 0) *(float*)&lds[pbase + 2304 + a * 4] = l;
  f32x4 l4 = *(const f32x4*)&lds[pbase + 2304 + h * 16];
  f32x4 inv;
  #pragma unroll
  for (int r = 0; r < 4; ++r) inv[r] = 1.0f / l4[r];
  const int b = bh >> 4, hd = bh & 15;
  #pragma unroll
  for (int n = 0; n < 4; ++n)
    #pragma unroll
    for (int r = 0; r < 4; ++r) {
      int t = q0 + wave * 16 + 4 * h + r;
      int col = hd * 64 + n * 16 + a;
      Y[((size_t)(b * Tn + t)) * Cn + col] = f2bf(o[n][r] * inv[r]);
    }
}

// ---------------------------------------------------------------------------
extern "C" void kernel_launch(void* const* d_in, const int* in_sizes, int n_in,
                              void* d_out, int out_size, void* d_ws, size_t ws_size,
                              hipStream_t stream) {
  const float* x      = (const float*)d_in[0];
  const float* W_attn = (const float*)d_in[1];
  const float* b_attn = (const float*)d_in[2];
  const float* W_proj = (const float*)d_in[3];
  const float* b_proj = (const float*)d_in[4];
  float* out = (float*)d_out;

  unsigned short* xb  = (unsigned short*)d_ws;          // [4096][1024]
  unsigned short* Wab = xb + (size_t)Mrows * Cn;        // [3072][1024]
  unsigned short* Wpb = Wab + (size_t)3 * Cn * Cn;      // [1024][1024]
  unsigned short* qkv = Wpb + (size_t)Cn * Cn;          // 3 planes of PL
  unsigned short* y   = qkv + 3 * PL;                   // [4096][1024]

  cast_bf16<<<(Mrows * Cn / 4 + 255) / 256, 256, 0, stream>>>(x, xb, Mrows * Cn / 4);
  transpose_cast<<<dim3(3 * Cn / 32, Cn / 32), dim3(32, 8), 0, stream>>>(W_attn, Wab, Cn, 3 * Cn);
  transpose_cast<<<dim3(Cn / 32, Cn / 32), dim3(32, 8), 0, stream>>>(W_proj, Wpb, Cn, Cn);

  gemm128<1><<<dim3(3 * Cn / 128, Mrows / 128), 256, 0, stream>>>(xb, Wab, b_attn, qkv, 3 * Cn, Cn);

  attn_mfma<<<dim3(Bn * Hn, Tn / 64), 256, 0, stream>>>(qkv, qkv + PL, qkv + 2 * PL, y);

  gemm128<2><<<dim3(Cn / 128, Mrows / 128), 256, 0, stream>>>(y, Wpb, b_proj, out, Cn, Cn);
}